// Round 3
// baseline (882.806 us; speedup 1.0000x reference)
//
#include <hip/hip_runtime.h>

#define DIM 128
#define BN_EPS 1e-5f
#define STAT_COPIES 64

typedef short short8 __attribute__((ext_vector_type(8)));   // 8 bf16 bit patterns
typedef float floatx4 __attribute__((ext_vector_type(4)));

__device__ __forceinline__ unsigned short f2bf(float f) {
    unsigned int u = __builtin_bit_cast(unsigned int, f);
    u += 0x7FFFu + ((u >> 16) & 1u);          // RNE (inputs are finite)
    return (unsigned short)(u >> 16);
}
__device__ __forceinline__ float bf2f(unsigned short h) {
    return __builtin_bit_cast(float, (unsigned int)h << 16);
}

// ---------------- K1: degree (atomic) + W->bf16 fragment conversion (merged) ----
// blocks [0, degB): deg ; blocks [degB, degB+16): convert_w.
// wfrag[((kt*8+nt)*64 + lane)*8 + j] = W[kt*32 + (lane>>4)*8 + j][nt*16 + (lane&15)]

__global__ __launch_bounds__(256) void deg_convw_kernel(
    const int* __restrict__ row, int* __restrict__ deg, int E, int degB,
    const float* __restrict__ W1, const float* __restrict__ W2,
    unsigned short* __restrict__ wfrag)
{
    if ((int)blockIdx.x < degB) {
        int e = blockIdx.x * 256 + threadIdx.x;
        if (e < E) atomicAdd(&deg[row[e]], 1);
    } else {
        int s = (blockIdx.x - degB) * 256 + threadIdx.x;   // 0..4095
        if (s >= 4096) return;
        int m  = s >> 11;
        int s2 = s & 2047;
        int kt = s2 >> 9;
        int nt = (s2 >> 6) & 7;
        int l  = s2 & 63;
        const float* W = m ? W2 : W1;
        unsigned short* o = wfrag + (size_t)m * 16384 + (size_t)s2 * 8;
        int k0 = kt * 32 + (l >> 4) * 8;
        int n0 = nt * 16 + (l & 15);
        #pragma unroll
        for (int j = 0; j < 8; ++j) o[j] = f2bf(W[(k0 + j) * DIM + n0]);
    }
}

// ---------------- K2: per-block exclusive scan over deg (+ fused dis) ----------

__global__ __launch_bounds__(256) void scan_block_kernel(const int* __restrict__ deg,
                                                         int* __restrict__ rowptr,
                                                         int* __restrict__ aux,
                                                         float* __restrict__ dis, int n) {
    __shared__ int ls[256];
    const int base = blockIdx.x * 1024;
    const int t = threadIdx.x;
    int v[4]; int s = 0;
    #pragma unroll
    for (int k = 0; k < 4; ++k) {
        int i = base + t * 4 + k;
        v[k] = (i < n) ? deg[i] : 0;
        s += v[k];
    }
    ls[t] = s;
    __syncthreads();
    for (int off = 1; off < 256; off <<= 1) {
        int x = (t >= off) ? ls[t - off] : 0;
        __syncthreads();
        ls[t] += x;
        __syncthreads();
    }
    int excl = ls[t] - s;
    if (t == 255) aux[blockIdx.x] = ls[255];
    #pragma unroll
    for (int k = 0; k < 4; ++k) {
        int i = base + t * 4 + k;
        if (i < n) {
            rowptr[i] = excl;
            dis[i] = rsqrtf((float)(v[k] + 1));   // +1 self-loop; always > 0
        }
        excl += v[k];
    }
}

// ---------------- K3: add aux prefix (computed per-block), build rp2 + cursor ----
// Folds the old scan_aux 1-block kernel: each block reduces aux[0..blockIdx-1]
// itself (<=255 entries, one LDS reduce). Writes rp2[i] = {start, end} packed
// (one 8B load in agg instead of two 4B) and cursor[i] = start for scatter.

__global__ __launch_bounds__(256) void add_offsets_kernel(
    const int* __restrict__ rowptr, const int* __restrict__ deg,
    const int* __restrict__ aux, int2* __restrict__ rp2,
    int* __restrict__ cursor, int n)
{
    __shared__ int red[256];
    const int t = threadIdx.x;
    red[t] = (t < (int)blockIdx.x) ? aux[t] : 0;   // blockIdx <= 255 by construction
    __syncthreads();
    for (int off = 128; off > 0; off >>= 1) {
        if (t < off) red[t] += red[t + off];
        __syncthreads();
    }
    const int base = red[0];
    #pragma unroll
    for (int k = 0; k < 4; ++k) {
        int i = blockIdx.x * 1024 + t * 4 + k;
        if (i < n) {
            int st = rowptr[i] + base;
            rp2[i] = make_int2(st, st + deg[i]);
            cursor[i] = st;
        }
    }
}

// ---------------- K4: scatter edges into CSR buckets + MFMA GEMM layer 1 (merged)
// blocks [0, scatB): scatter ; blocks [scatB, ...): gemm1.
// scatter is atomic/latency-bound, gemm1 is BW-bound -> complementary overlap.

__global__ __launch_bounds__(256) void scatter_gemm1_kernel(
    // scatter args
    const int* __restrict__ row, const int* __restrict__ col,
    const float* __restrict__ dis, int* __restrict__ cursor,
    int2* __restrict__ epack, int E, int scatB,
    // gemm args
    const float* __restrict__ A, const unsigned short* __restrict__ wfrag,
    unsigned short* __restrict__ C, int n)
{
    if ((int)blockIdx.x < scatB) {
        int e = blockIdx.x * 256 + threadIdx.x;
        if (e >= E) return;
        int r = row[e], c = col[e];
        int pos = atomicAdd(&cursor[r], 1);
        float nrm = dis[r] * dis[c];
        epack[pos] = make_int2(c, __builtin_bit_cast(int, nrm));
    } else {
        __shared__ unsigned short sA[64][136];
        const int tid  = threadIdx.x;
        const int row0 = (blockIdx.x - scatB) * 64;

        #pragma unroll
        for (int l = 0; l < 8; ++l) {
            int idx = tid + l * 256;
            int r   = idx >> 5;
            int c4  = (idx & 31) * 4;
            float4 v;
            if (row0 + r < n) v = *(const float4*)(A + (size_t)(row0 + r) * DIM + c4);
            else              v = make_float4(0.f, 0.f, 0.f, 0.f);
            unsigned int lo = (unsigned int)f2bf(v.x) | ((unsigned int)f2bf(v.y) << 16);
            unsigned int hi = (unsigned int)f2bf(v.z) | ((unsigned int)f2bf(v.w) << 16);
            *(uint2*)(&sA[r][c4]) = make_uint2(lo, hi);
        }
        __syncthreads();

        const int wave = tid >> 6;
        const int lane = tid & 63;
        const int m    = lane & 15;
        const int quad = lane >> 4;
        const int rowA = wave * 16 + m;

        short8 af[4];
        #pragma unroll
        for (int kt = 0; kt < 4; ++kt)
            af[kt] = *(const short8*)(&sA[rowA][kt * 32 + quad * 8]);

        floatx4 acc[8];
        #pragma unroll
        for (int nt = 0; nt < 8; ++nt) acc[nt] = (floatx4){0.f, 0.f, 0.f, 0.f};

        #pragma unroll
        for (int nt = 0; nt < 8; ++nt)
            #pragma unroll
            for (int kt = 0; kt < 4; ++kt) {
                short8 bfr = *(const short8*)(wfrag + ((size_t)(kt * 8 + nt) * 64 + lane) * 8);
                acc[nt] = __builtin_amdgcn_mfma_f32_16x16x32_bf16(af[kt], bfr, acc[nt], 0, 0, 0);
            }

        #pragma unroll
        for (int nt = 0; nt < 8; ++nt)
            #pragma unroll
            for (int r = 0; r < 4; ++r) {
                int rr = row0 + wave * 16 + quad * 4 + r;
                if (rr < n) C[(size_t)rr * DIM + nt * 16 + m] = f2bf(acc[nt][r]);
            }
    }
}

// ---------------- K6: MFMA GEMM, bf16 A input + fused BN/ReLU (layer 2) --------
// BN folded to scale/shift (precomputed in agg1's finalize): relu(f*scale+shift)

__global__ __launch_bounds__(256) void gemm_mfma_bn_kernel(
    const unsigned short* __restrict__ A, const unsigned short* __restrict__ wfrag,
    unsigned short* __restrict__ C, int n,
    const float* __restrict__ mi)   // mi[0..127]=scale, mi[128..255]=shift
{
    __shared__ unsigned short sA[64][136];
    const int tid  = threadIdx.x;
    const int row0 = blockIdx.x * 64;

    #pragma unroll
    for (int l = 0; l < 4; ++l) {
        int idx = tid + l * 256;          // 0..1023, 16B chunks
        int r   = idx >> 4;
        int c8  = (idx & 15) * 8;
        uint4 u = make_uint4(0, 0, 0, 0);
        if (row0 + r < n) u = *(const uint4*)(A + (size_t)(row0 + r) * DIM + c8);
        float f[8] = { bf2f((unsigned short)(u.x & 0xffff)), bf2f((unsigned short)(u.x >> 16)),
                       bf2f((unsigned short)(u.y & 0xffff)), bf2f((unsigned short)(u.y >> 16)),
                       bf2f((unsigned short)(u.z & 0xffff)), bf2f((unsigned short)(u.z >> 16)),
                       bf2f((unsigned short)(u.w & 0xffff)), bf2f((unsigned short)(u.w >> 16)) };
        #pragma unroll
        for (int k = 0; k < 8; ++k) {
            int c = c8 + k;
            f[k] = fmaxf(fmaf(f[k], mi[c], mi[128 + c]), 0.f);
        }
        uint4 o;
        o.x = (unsigned int)f2bf(f[0]) | ((unsigned int)f2bf(f[1]) << 16);
        o.y = (unsigned int)f2bf(f[2]) | ((unsigned int)f2bf(f[3]) << 16);
        o.z = (unsigned int)f2bf(f[4]) | ((unsigned int)f2bf(f[5]) << 16);
        o.w = (unsigned int)f2bf(f[6]) | ((unsigned int)f2bf(f[7]) << 16);
        *(uint4*)(&sA[r][c8]) = o;
    }
    __syncthreads();

    const int wave = tid >> 6;
    const int lane = tid & 63;
    const int m    = lane & 15;
    const int quad = lane >> 4;
    const int rowA = wave * 16 + m;

    short8 af[4];
    #pragma unroll
    for (int kt = 0; kt < 4; ++kt)
        af[kt] = *(const short8*)(&sA[rowA][kt * 32 + quad * 8]);

    floatx4 acc[8];
    #pragma unroll
    for (int nt = 0; nt < 8; ++nt) acc[nt] = (floatx4){0.f, 0.f, 0.f, 0.f};

    #pragma unroll
    for (int nt = 0; nt < 8; ++nt)
        #pragma unroll
        for (int kt = 0; kt < 4; ++kt) {
            short8 bfr = *(const short8*)(wfrag + ((size_t)(kt * 8 + nt) * 64 + lane) * 8);
            acc[nt] = __builtin_amdgcn_mfma_f32_16x16x32_bf16(af[kt], bfr, acc[nt], 0, 0, 0);
        }

    #pragma unroll
    for (int nt = 0; nt < 8; ++nt)
        #pragma unroll
        for (int r = 0; r < 4; ++r) {
            int rr = row0 + wave * 16 + quad * 4 + r;
            if (rr < n) C[(size_t)rr * DIM + nt * 16 + m] = f2bf(acc[nt][r]);
        }
}

// ---------------- K5/K7: CSR aggregation ----------------
// 16 lanes/node, 8 ch/lane. out[i] = sum_e hw[col_e]*norm_e + hw[i]*dis_i^2 + bias.
// Uniform predicated unroll-8 loop: index clamped to pe-1, weight 0 for pad slots
// (fmaf w=0 leaves acc bit-identical; dup gathers hit the same hot line).
// STATS: LDS reduce + atomics over 64 spread copies; LAST-DONE block computes the
// BN scale/shift in-kernel (agent-scope loads for cross-XCD visibility).

__device__ __forceinline__ void acc8(float* acc, uint4 u, float w) {
    unsigned int a[4] = {u.x, u.y, u.z, u.w};
    #pragma unroll
    for (int k = 0; k < 4; ++k) {
        acc[2*k]   = fmaf(bf2f((unsigned short)(a[k] & 0xffff)), w, acc[2*k]);
        acc[2*k+1] = fmaf(bf2f((unsigned short)(a[k] >> 16)),    w, acc[2*k+1]);
    }
}

template <bool OUT_BF16, bool STATS>
__global__ __launch_bounds__(256) void agg_csr_kernel(
    const unsigned short* __restrict__ hw, const float* __restrict__ dis,
    const int2* __restrict__ rp2, const int2* __restrict__ epack,
    const float* __restrict__ bias, void* __restrict__ out_, int n,
    float* __restrict__ stat, unsigned int* __restrict__ donecnt,
    const float* __restrict__ gamma, const float* __restrict__ beta,
    float* __restrict__ mi)
{
    const int sub  = threadIdx.x >> 4;        // 0..15 node slot in block
    const int l    = threadIdx.x & 15;
    const int node = blockIdx.x * 16 + sub;
    const bool valid = node < n;
    const int j = l * 8;

    float acc[8];
    #pragma unroll
    for (int k = 0; k < 8; ++k) acc[k] = 0.f;

    if (valid) {
        const int2 rp = rp2[node];            // one 8B load: {start, end}
        {   // self-loop term: hw[i] * dis_i^2
            const float d = dis[node];
            uint4 u = *(const uint4*)(hw + (size_t)node * DIM + j);
            acc8(acc, u, d * d);
        }

        const int pe = rp.y;
        for (int p = rp.x; p < pe; p += 8) {
            const int pm = pe - 1;
            int2 e[8];
            #pragma unroll
            for (int k = 0; k < 8; ++k) {
                int pk = p + k;
                e[k] = epack[pk < pm ? pk : pm];
            }
            uint4 u[8];
            #pragma unroll
            for (int k = 0; k < 8; ++k)
                u[k] = *(const uint4*)(hw + (size_t)e[k].x * DIM + j);
            #pragma unroll
            for (int k = 0; k < 8; ++k) {
                float w = (p + k < pe) ? __builtin_bit_cast(float, e[k].y) : 0.f;
                acc8(acc, u[k], w);
            }
        }

        float4 b0 = *(const float4*)(bias + j);
        float4 b1 = *(const float4*)(bias + j + 4);
        acc[0] += b0.x; acc[1] += b0.y; acc[2] += b0.z; acc[3] += b0.w;
        acc[4] += b1.x; acc[5] += b1.y; acc[6] += b1.z; acc[7] += b1.w;

        if (OUT_BF16) {
            unsigned short* out = (unsigned short*)out_;
            uint4 o;
            o.x = (unsigned int)f2bf(acc[0]) | ((unsigned int)f2bf(acc[1]) << 16);
            o.y = (unsigned int)f2bf(acc[2]) | ((unsigned int)f2bf(acc[3]) << 16);
            o.z = (unsigned int)f2bf(acc[4]) | ((unsigned int)f2bf(acc[5]) << 16);
            o.w = (unsigned int)f2bf(acc[6]) | ((unsigned int)f2bf(acc[7]) << 16);
            *(uint4*)(out + (size_t)node * DIM + j) = o;
        } else {
            float* out = (float*)out_;
            *(float4*)(out + (size_t)node * DIM + j)     = make_float4(acc[0], acc[1], acc[2], acc[3]);
            *(float4*)(out + (size_t)node * DIM + j + 4) = make_float4(acc[4], acc[5], acc[6], acc[7]);
        }
    }

    if constexpr (STATS) {
        // row padded to 257 floats: 4-way write conflicts max, reads ~free.
        __shared__ float red[16][257];
        __shared__ int lastFlag;
        #pragma unroll
        for (int k = 0; k < 8; ++k) {
            float a = valid ? acc[k] : 0.f;
            red[sub][j + k]       = a;
            red[sub][128 + j + k] = a * a;
        }
        __syncthreads();
        float t = 0.f;
        #pragma unroll
        for (int r = 0; r < 16; ++r) t += red[r][threadIdx.x];
        atomicAdd(&stat[(blockIdx.x & (STAT_COPIES - 1)) * 256 + threadIdx.x], t);

        // last-done block computes BN scale/shift (folds old bn_finalize launch)
        __threadfence();
        if (threadIdx.x == 0) {
            unsigned prev = atomicAdd(donecnt, 1u);
            lastFlag = (prev == gridDim.x - 1) ? 1 : 0;
        }
        __syncthreads();
        if (lastFlag && threadIdx.x < DIM) {
            const int c = threadIdx.x;
            float s = 0.f, q = 0.f;
            for (int cp = 0; cp < STAT_COPIES; ++cp) {
                s += __hip_atomic_load(&stat[cp * 256 + c],       __ATOMIC_RELAXED,
                                       __HIP_MEMORY_SCOPE_AGENT);
                q += __hip_atomic_load(&stat[cp * 256 + 128 + c], __ATOMIC_RELAXED,
                                       __HIP_MEMORY_SCOPE_AGENT);
            }
            float mean  = s / (float)n;
            float var   = q / (float)n - mean * mean;
            float istd  = rsqrtf(var + BN_EPS);
            float scale = gamma[c] * istd;
            mi[c]       = scale;
            mi[DIM + c] = fmaf(-mean, scale, beta[c]);   // shift
        }
    }
}

// ---------------- launch ----------------

extern "C" void kernel_launch(void* const* d_in, const int* in_sizes, int n_in,
                              void* d_out, int out_size, void* d_ws, size_t ws_size,
                              hipStream_t stream)
{
    const float* x      = (const float*)d_in[0];
    const int*   ei     = (const int*)  d_in[1];
    const float* W1     = (const float*)d_in[2];
    const float* b1     = (const float*)d_in[3];
    const float* gamma1 = (const float*)d_in[4];
    const float* beta1  = (const float*)d_in[5];
    const float* W2     = (const float*)d_in[6];
    const float* b2     = (const float*)d_in[7];
    float* out = (float*)d_out;

    const int N = in_sizes[0] / DIM;   // 100000
    const int E = in_sizes[1] / 2;     // 600000
    const int* row = ei;
    const int* col = ei + E;

    const int NB    = (N + 1023) / 1024;   // <= 256 (N <= 262144)
    const int degB  = (E + 255) / 256;
    const int gemmB = (N + 63) / 64;
    const int aggB  = (N + 15) / 16;

    // Workspace layout (8B-alignment-safe ordering). Zeroed region is contiguous:
    unsigned short* hw    = (unsigned short*)d_ws;         // N*128 bf16
    unsigned short* h1    = hw + (size_t)N * DIM;          // N*128 bf16
    int2*  epack  = (int2*)(h1 + (size_t)N * DIM);         // E (8B each)
    int2*  rp2    = epack + E;                             // N {start,end}
    unsigned short* wfrag = (unsigned short*)(rp2 + N);    // 2*16384 bf16
    float* dis    = (float*)(wfrag + 2 * 16384);           // N
    int*   cursor = (int*)(dis + N);                       // N
    int*   rowptr = cursor + N;                            // N (scratch, per-block scan)
    int*   aux    = rowptr + N;                            // 256
    float* mi     = (float*)(aux + 256);                   // 256
    // ---- zeroed region start ----
    int*   deg    = (int*)(mi + 256);                      // N
    float* stat   = (float*)(deg + N);                     // 64*256
    unsigned int* donecnt = (unsigned int*)(stat + STAT_COPIES * 256);  // 1 (+pad)
    const size_t zero_bytes = (size_t)N * 4 + (size_t)STAT_COPIES * 256 * 4 + 16;

    hipMemsetAsync(deg, 0, zero_bytes, stream);

    // K1: degree atomics + W conversion (independent, merged)
    deg_convw_kernel<<<degB + 16, 256, 0, stream>>>(row, deg, E, degB, W1, W2, wfrag);
    // K2: per-block exclusive scan (+ dis)
    scan_block_kernel<<<NB, 256, 0, stream>>>(deg, rowptr, aux, dis, N);
    // K3: cross-block offsets (self-computed aux prefix), rp2 + cursor
    add_offsets_kernel<<<NB, 256, 0, stream>>>(rowptr, deg, aux, rp2, cursor, N);
    // K4: edge scatter (latency-bound) overlapped with gemm1 (BW-bound)
    scatter_gemm1_kernel<<<degB + gemmB, 256, 0, stream>>>(row, col, dis, cursor, epack,
                                                           E, degB, x, wfrag, hw, N);
    // K5: agg layer 1 + fused BN stats + last-block finalize (scale/shift -> mi)
    agg_csr_kernel<true, true><<<aggB, 256, 0, stream>>>(hw, dis, rp2, epack, b1, h1, N,
                                                         stat, donecnt, gamma1, beta1, mi);
    // K6: gemm2 with fused BN(scale,shift)+ReLU on input
    gemm_mfma_bn_kernel<<<gemmB, 256, 0, stream>>>(h1, wfrag + 16384, hw, N, mi);
    // K7: agg layer 2 -> fp32 output
    agg_csr_kernel<false, false><<<aggB, 256, 0, stream>>>(hw, dis, rp2, epack, b2, out, N,
                                                           nullptr, nullptr, nullptr, nullptr,
                                                           nullptr);
}

// Round 4
// 273.492 us; speedup vs baseline: 3.2279x; 3.2279x over previous
//
#include <hip/hip_runtime.h>

#define DIM 128
#define BN_EPS 1e-5f
#define STAT_COPIES 64

typedef short short8 __attribute__((ext_vector_type(8)));   // 8 bf16 bit patterns
typedef float floatx4 __attribute__((ext_vector_type(4)));

__device__ __forceinline__ unsigned short f2bf(float f) {
    unsigned int u = __builtin_bit_cast(unsigned int, f);
    u += 0x7FFFu + ((u >> 16) & 1u);          // RNE (inputs are finite)
    return (unsigned short)(u >> 16);
}
__device__ __forceinline__ float bf2f(unsigned short h) {
    return __builtin_bit_cast(float, (unsigned int)h << 16);
}

// ---------------- K1: degree (atomic) + W->bf16 fragment conversion (merged) ----
// blocks [0, degB): deg ; blocks [degB, degB+16): convert_w.
// wfrag[((kt*8+nt)*64 + lane)*8 + j] = W[kt*32 + (lane>>4)*8 + j][nt*16 + (lane&15)]

__global__ __launch_bounds__(256) void deg_convw_kernel(
    const int* __restrict__ row, int* __restrict__ deg, int E, int degB,
    const float* __restrict__ W1, const float* __restrict__ W2,
    unsigned short* __restrict__ wfrag)
{
    if ((int)blockIdx.x < degB) {
        int e = blockIdx.x * 256 + threadIdx.x;
        if (e < E) atomicAdd(&deg[row[e]], 1);
    } else {
        int s = (blockIdx.x - degB) * 256 + threadIdx.x;   // 0..4095
        if (s >= 4096) return;
        int m  = s >> 11;
        int s2 = s & 2047;
        int kt = s2 >> 9;
        int nt = (s2 >> 6) & 7;
        int l  = s2 & 63;
        const float* W = m ? W2 : W1;
        unsigned short* o = wfrag + (size_t)m * 16384 + (size_t)s2 * 8;
        int k0 = kt * 32 + (l >> 4) * 8;
        int n0 = nt * 16 + (l & 15);
        #pragma unroll
        for (int j = 0; j < 8; ++j) o[j] = f2bf(W[(k0 + j) * DIM + n0]);
    }
}

// ---------------- K2: per-block exclusive scan over deg (+ fused dis) ----------

__global__ __launch_bounds__(256) void scan_block_kernel(const int* __restrict__ deg,
                                                         int* __restrict__ rowptr,
                                                         int* __restrict__ aux,
                                                         float* __restrict__ dis, int n) {
    __shared__ int ls[256];
    const int base = blockIdx.x * 1024;
    const int t = threadIdx.x;
    int v[4]; int s = 0;
    #pragma unroll
    for (int k = 0; k < 4; ++k) {
        int i = base + t * 4 + k;
        v[k] = (i < n) ? deg[i] : 0;
        s += v[k];
    }
    ls[t] = s;
    __syncthreads();
    for (int off = 1; off < 256; off <<= 1) {
        int x = (t >= off) ? ls[t - off] : 0;
        __syncthreads();
        ls[t] += x;
        __syncthreads();
    }
    int excl = ls[t] - s;
    if (t == 255) aux[blockIdx.x] = ls[255];
    #pragma unroll
    for (int k = 0; k < 4; ++k) {
        int i = base + t * 4 + k;
        if (i < n) {
            rowptr[i] = excl;
            dis[i] = rsqrtf((float)(v[k] + 1));   // +1 self-loop; always > 0
        }
        excl += v[k];
    }
}

// ---------------- K3: add aux prefix (computed per-block), build rp2 + cursor ----
// Each block reduces aux[0..blockIdx-1] itself (<=255 entries, one LDS reduce).
// Writes rp2[i] = {start, end} packed and cursor[i] = start for scatter.

__global__ __launch_bounds__(256) void add_offsets_kernel(
    const int* __restrict__ rowptr, const int* __restrict__ deg,
    const int* __restrict__ aux, int2* __restrict__ rp2,
    int* __restrict__ cursor, int n)
{
    __shared__ int red[256];
    const int t = threadIdx.x;
    red[t] = (t < (int)blockIdx.x) ? aux[t] : 0;   // blockIdx <= 255 by construction
    __syncthreads();
    for (int off = 128; off > 0; off >>= 1) {
        if (t < off) red[t] += red[t + off];
        __syncthreads();
    }
    const int base = red[0];
    #pragma unroll
    for (int k = 0; k < 4; ++k) {
        int i = blockIdx.x * 1024 + t * 4 + k;
        if (i < n) {
            int st = rowptr[i] + base;
            rp2[i] = make_int2(st, st + deg[i]);
            cursor[i] = st;
        }
    }
}

// ---------------- K4: scatter edges into CSR buckets + MFMA GEMM layer 1 (merged)
// blocks [0, scatB): scatter ; blocks [scatB, ...): gemm1.
// scatter is atomic/latency-bound, gemm1 is BW-bound -> complementary overlap.

__global__ __launch_bounds__(256) void scatter_gemm1_kernel(
    // scatter args
    const int* __restrict__ row, const int* __restrict__ col,
    const float* __restrict__ dis, int* __restrict__ cursor,
    int2* __restrict__ epack, int E, int scatB,
    // gemm args
    const float* __restrict__ A, const unsigned short* __restrict__ wfrag,
    unsigned short* __restrict__ C, int n)
{
    if ((int)blockIdx.x < scatB) {
        int e = blockIdx.x * 256 + threadIdx.x;
        if (e >= E) return;
        int r = row[e], c = col[e];
        int pos = atomicAdd(&cursor[r], 1);
        float nrm = dis[r] * dis[c];
        epack[pos] = make_int2(c, __builtin_bit_cast(int, nrm));
    } else {
        __shared__ unsigned short sA[64][136];
        const int tid  = threadIdx.x;
        const int row0 = (blockIdx.x - scatB) * 64;

        #pragma unroll
        for (int l = 0; l < 8; ++l) {
            int idx = tid + l * 256;
            int r   = idx >> 5;
            int c4  = (idx & 31) * 4;
            float4 v;
            if (row0 + r < n) v = *(const float4*)(A + (size_t)(row0 + r) * DIM + c4);
            else              v = make_float4(0.f, 0.f, 0.f, 0.f);
            unsigned int lo = (unsigned int)f2bf(v.x) | ((unsigned int)f2bf(v.y) << 16);
            unsigned int hi = (unsigned int)f2bf(v.z) | ((unsigned int)f2bf(v.w) << 16);
            *(uint2*)(&sA[r][c4]) = make_uint2(lo, hi);
        }
        __syncthreads();

        const int wave = tid >> 6;
        const int lane = tid & 63;
        const int m    = lane & 15;
        const int quad = lane >> 4;
        const int rowA = wave * 16 + m;

        short8 af[4];
        #pragma unroll
        for (int kt = 0; kt < 4; ++kt)
            af[kt] = *(const short8*)(&sA[rowA][kt * 32 + quad * 8]);

        floatx4 acc[8];
        #pragma unroll
        for (int nt = 0; nt < 8; ++nt) acc[nt] = (floatx4){0.f, 0.f, 0.f, 0.f};

        #pragma unroll
        for (int nt = 0; nt < 8; ++nt)
            #pragma unroll
            for (int kt = 0; kt < 4; ++kt) {
                short8 bfr = *(const short8*)(wfrag + ((size_t)(kt * 8 + nt) * 64 + lane) * 8);
                acc[nt] = __builtin_amdgcn_mfma_f32_16x16x32_bf16(af[kt], bfr, acc[nt], 0, 0, 0);
            }

        #pragma unroll
        for (int nt = 0; nt < 8; ++nt)
            #pragma unroll
            for (int r = 0; r < 4; ++r) {
                int rr = row0 + wave * 16 + quad * 4 + r;
                if (rr < n) C[(size_t)rr * DIM + nt * 16 + m] = f2bf(acc[nt][r]);
            }
    }
}

// ---------------- K6: MFMA GEMM, bf16 A input + fused BN/ReLU (layer 2) --------
// BN folded to scale/shift (precomputed in bn_finalize): relu(f*scale+shift)

__global__ __launch_bounds__(256) void gemm_mfma_bn_kernel(
    const unsigned short* __restrict__ A, const unsigned short* __restrict__ wfrag,
    unsigned short* __restrict__ C, int n,
    const float* __restrict__ mi)   // mi[0..127]=scale, mi[128..255]=shift
{
    __shared__ unsigned short sA[64][136];
    const int tid  = threadIdx.x;
    const int row0 = blockIdx.x * 64;

    #pragma unroll
    for (int l = 0; l < 4; ++l) {
        int idx = tid + l * 256;          // 0..1023, 16B chunks
        int r   = idx >> 4;
        int c8  = (idx & 15) * 8;
        uint4 u = make_uint4(0, 0, 0, 0);
        if (row0 + r < n) u = *(const uint4*)(A + (size_t)(row0 + r) * DIM + c8);
        float f[8] = { bf2f((unsigned short)(u.x & 0xffff)), bf2f((unsigned short)(u.x >> 16)),
                       bf2f((unsigned short)(u.y & 0xffff)), bf2f((unsigned short)(u.y >> 16)),
                       bf2f((unsigned short)(u.z & 0xffff)), bf2f((unsigned short)(u.z >> 16)),
                       bf2f((unsigned short)(u.w & 0xffff)), bf2f((unsigned short)(u.w >> 16)) };
        #pragma unroll
        for (int k = 0; k < 8; ++k) {
            int c = c8 + k;
            f[k] = fmaxf(fmaf(f[k], mi[c], mi[128 + c]), 0.f);
        }
        uint4 o;
        o.x = (unsigned int)f2bf(f[0]) | ((unsigned int)f2bf(f[1]) << 16);
        o.y = (unsigned int)f2bf(f[2]) | ((unsigned int)f2bf(f[3]) << 16);
        o.z = (unsigned int)f2bf(f[4]) | ((unsigned int)f2bf(f[5]) << 16);
        o.w = (unsigned int)f2bf(f[6]) | ((unsigned int)f2bf(f[7]) << 16);
        *(uint4*)(&sA[r][c8]) = o;
    }
    __syncthreads();

    const int wave = tid >> 6;
    const int lane = tid & 63;
    const int m    = lane & 15;
    const int quad = lane >> 4;
    const int rowA = wave * 16 + m;

    short8 af[4];
    #pragma unroll
    for (int kt = 0; kt < 4; ++kt)
        af[kt] = *(const short8*)(&sA[rowA][kt * 32 + quad * 8]);

    floatx4 acc[8];
    #pragma unroll
    for (int nt = 0; nt < 8; ++nt) acc[nt] = (floatx4){0.f, 0.f, 0.f, 0.f};

    #pragma unroll
    for (int nt = 0; nt < 8; ++nt)
        #pragma unroll
        for (int kt = 0; kt < 4; ++kt) {
            short8 bfr = *(const short8*)(wfrag + ((size_t)(kt * 8 + nt) * 64 + lane) * 8);
            acc[nt] = __builtin_amdgcn_mfma_f32_16x16x32_bf16(af[kt], bfr, acc[nt], 0, 0, 0);
        }

    #pragma unroll
    for (int nt = 0; nt < 8; ++nt)
        #pragma unroll
        for (int r = 0; r < 4; ++r) {
            int rr = row0 + wave * 16 + quad * 4 + r;
            if (rr < n) C[(size_t)rr * DIM + nt * 16 + m] = f2bf(acc[nt][r]);
        }
}

// ---------------- K5/K7: CSR aggregation ----------------
// 16 lanes/node, 8 ch/lane. out[i] = sum_e hw[col_e]*norm_e + hw[i]*dis_i^2 + bias.
// Uniform predicated unroll-8 loop: index clamped to pe-1, weight 0 for pad slots.
// STATS: LDS reduce + atomics over 64 spread copies. NO per-block threadfence
// (round-3 lesson: 6250x buffer_wbl2 serialized at the TCC = +620us); the BN
// finalize lives in its own 1-block kernel, kernel boundary = visibility.

__device__ __forceinline__ void acc8(float* acc, uint4 u, float w) {
    unsigned int a[4] = {u.x, u.y, u.z, u.w};
    #pragma unroll
    for (int k = 0; k < 4; ++k) {
        acc[2*k]   = fmaf(bf2f((unsigned short)(a[k] & 0xffff)), w, acc[2*k]);
        acc[2*k+1] = fmaf(bf2f((unsigned short)(a[k] >> 16)),    w, acc[2*k+1]);
    }
}

template <bool OUT_BF16, bool STATS>
__global__ __launch_bounds__(256) void agg_csr_kernel(
    const unsigned short* __restrict__ hw, const float* __restrict__ dis,
    const int2* __restrict__ rp2, const int2* __restrict__ epack,
    const float* __restrict__ bias, void* __restrict__ out_, int n,
    float* __restrict__ stat)
{
    const int sub  = threadIdx.x >> 4;        // 0..15 node slot in block
    const int l    = threadIdx.x & 15;
    const int node = blockIdx.x * 16 + sub;
    const bool valid = node < n;
    const int j = l * 8;

    float acc[8];
    #pragma unroll
    for (int k = 0; k < 8; ++k) acc[k] = 0.f;

    if (valid) {
        const int2 rp = rp2[node];            // one 8B load: {start, end}
        {   // self-loop term: hw[i] * dis_i^2
            const float d = dis[node];
            uint4 u = *(const uint4*)(hw + (size_t)node * DIM + j);
            acc8(acc, u, d * d);
        }

        const int pe = rp.y;
        for (int p = rp.x; p < pe; p += 8) {
            const int pm = pe - 1;
            int2 e[8];
            #pragma unroll
            for (int k = 0; k < 8; ++k) {
                int pk = p + k;
                e[k] = epack[pk < pm ? pk : pm];
            }
            uint4 u[8];
            #pragma unroll
            for (int k = 0; k < 8; ++k)
                u[k] = *(const uint4*)(hw + (size_t)e[k].x * DIM + j);
            #pragma unroll
            for (int k = 0; k < 8; ++k) {
                float w = (p + k < pe) ? __builtin_bit_cast(float, e[k].y) : 0.f;
                acc8(acc, u[k], w);
            }
        }

        float4 b0 = *(const float4*)(bias + j);
        float4 b1 = *(const float4*)(bias + j + 4);
        acc[0] += b0.x; acc[1] += b0.y; acc[2] += b0.z; acc[3] += b0.w;
        acc[4] += b1.x; acc[5] += b1.y; acc[6] += b1.z; acc[7] += b1.w;

        if (OUT_BF16) {
            unsigned short* out = (unsigned short*)out_;
            uint4 o;
            o.x = (unsigned int)f2bf(acc[0]) | ((unsigned int)f2bf(acc[1]) << 16);
            o.y = (unsigned int)f2bf(acc[2]) | ((unsigned int)f2bf(acc[3]) << 16);
            o.z = (unsigned int)f2bf(acc[4]) | ((unsigned int)f2bf(acc[5]) << 16);
            o.w = (unsigned int)f2bf(acc[6]) | ((unsigned int)f2bf(acc[7]) << 16);
            *(uint4*)(out + (size_t)node * DIM + j) = o;
        } else {
            float* out = (float*)out_;
            *(float4*)(out + (size_t)node * DIM + j)     = make_float4(acc[0], acc[1], acc[2], acc[3]);
            *(float4*)(out + (size_t)node * DIM + j + 4) = make_float4(acc[4], acc[5], acc[6], acc[7]);
        }
    }

    if constexpr (STATS) {
        // row padded to 257 floats: 4-way write conflicts max, reads ~free.
        __shared__ float red[16][257];
        #pragma unroll
        for (int k = 0; k < 8; ++k) {
            float a = valid ? acc[k] : 0.f;
            red[sub][j + k]       = a;
            red[sub][128 + j + k] = a * a;
        }
        __syncthreads();
        float t = 0.f;
        #pragma unroll
        for (int r = 0; r < 16; ++r) t += red[r][threadIdx.x];
        atomicAdd(&stat[(blockIdx.x & (STAT_COPIES - 1)) * 256 + threadIdx.x], t);
    }
}

// ---------------- BN finalize: fold stats into scale/shift ----------------

__global__ void bn_finalize_kernel(const float* __restrict__ stat,
                                   const float* __restrict__ gamma,
                                   const float* __restrict__ beta,
                                   float* __restrict__ mi, int n) {
    int c = threadIdx.x;
    if (c < DIM) {
        float s = 0.f, q = 0.f;
        #pragma unroll 4
        for (int cp = 0; cp < STAT_COPIES; ++cp) {
            s += stat[cp * 256 + c];
            q += stat[cp * 256 + 128 + c];
        }
        float mean  = s / (float)n;
        float var   = q / (float)n - mean * mean;
        float istd  = rsqrtf(var + BN_EPS);
        float scale = gamma[c] * istd;
        mi[c]       = scale;
        mi[DIM + c] = fmaf(-mean, scale, beta[c]);   // shift
    }
}

// ---------------- launch ----------------

extern "C" void kernel_launch(void* const* d_in, const int* in_sizes, int n_in,
                              void* d_out, int out_size, void* d_ws, size_t ws_size,
                              hipStream_t stream)
{
    const float* x      = (const float*)d_in[0];
    const int*   ei     = (const int*)  d_in[1];
    const float* W1     = (const float*)d_in[2];
    const float* b1     = (const float*)d_in[3];
    const float* gamma1 = (const float*)d_in[4];
    const float* beta1  = (const float*)d_in[5];
    const float* W2     = (const float*)d_in[6];
    const float* b2     = (const float*)d_in[7];
    float* out = (float*)d_out;

    const int N = in_sizes[0] / DIM;   // 100000
    const int E = in_sizes[1] / 2;     // 600000
    const int* row = ei;
    const int* col = ei + E;

    const int NB    = (N + 1023) / 1024;   // <= 256 (N <= 262144)
    const int degB  = (E + 255) / 256;
    const int gemmB = (N + 63) / 64;
    const int aggB  = (N + 15) / 16;

    // Workspace layout (8B-alignment-safe ordering). Zeroed region is contiguous:
    unsigned short* hw    = (unsigned short*)d_ws;         // N*128 bf16
    unsigned short* h1    = hw + (size_t)N * DIM;          // N*128 bf16
    int2*  epack  = (int2*)(h1 + (size_t)N * DIM);         // E (8B each)
    int2*  rp2    = epack + E;                             // N {start,end}
    unsigned short* wfrag = (unsigned short*)(rp2 + N);    // 2*16384 bf16
    float* dis    = (float*)(wfrag + 2 * 16384);           // N
    int*   cursor = (int*)(dis + N);                       // N
    int*   rowptr = cursor + N;                            // N (scratch, per-block scan)
    int*   aux    = rowptr + N;                            // 256
    float* mi     = (float*)(aux + 256);                   // 256
    // ---- zeroed region start ----
    int*   deg    = (int*)(mi + 256);                      // N
    float* stat   = (float*)(deg + N);                     // 64*256
    const size_t zero_bytes = (size_t)N * 4 + (size_t)STAT_COPIES * 256 * 4;

    hipMemsetAsync(deg, 0, zero_bytes, stream);

    // K1: degree atomics + W conversion (independent, merged)
    deg_convw_kernel<<<degB + 16, 256, 0, stream>>>(row, deg, E, degB, W1, W2, wfrag);
    // K2: per-block exclusive scan (+ dis)
    scan_block_kernel<<<NB, 256, 0, stream>>>(deg, rowptr, aux, dis, N);
    // K3: cross-block offsets (self-computed aux prefix), rp2 + cursor
    add_offsets_kernel<<<NB, 256, 0, stream>>>(rowptr, deg, aux, rp2, cursor, N);
    // K4: edge scatter (latency-bound) overlapped with gemm1 (BW-bound)
    scatter_gemm1_kernel<<<degB + gemmB, 256, 0, stream>>>(row, col, dis, cursor, epack,
                                                           E, degB, x, wfrag, hw, N);
    // K5: agg layer 1 + fused BN stats (spread atomics, no fence)
    agg_csr_kernel<true, true><<<aggB, 256, 0, stream>>>(hw, dis, rp2, epack, b1, h1, N,
                                                         stat);
    // K5b: fold stats -> BN scale/shift (1 tiny block; kernel boundary = coherence)
    bn_finalize_kernel<<<1, DIM, 0, stream>>>(stat, gamma1, beta1, mi, N);
    // K6: gemm2 with fused BN(scale,shift)+ReLU on input
    gemm_mfma_bn_kernel<<<gemmB, 256, 0, stream>>>(h1, wfrag + 16384, hw, N, mi);
    // K7: agg layer 2 -> fp32 output
    agg_csr_kernel<false, false><<<aggB, 256, 0, stream>>>(hw, dis, rp2, epack, b2, out, N,
                                                           nullptr);
}

// Round 5
// 262.674 us; speedup vs baseline: 3.3608x; 1.0412x over previous
//
#include <hip/hip_runtime.h>

#define DIM 128
#define BN_EPS 1e-5f
#define STAT_COPIES 64

typedef short short8 __attribute__((ext_vector_type(8)));   // 8 bf16 bit patterns
typedef float floatx4 __attribute__((ext_vector_type(4)));

__device__ __forceinline__ unsigned short f2bf(float f) {
    unsigned int u = __builtin_bit_cast(unsigned int, f);
    u += 0x7FFFu + ((u >> 16) & 1u);          // RNE (inputs are finite)
    return (unsigned short)(u >> 16);
}
__device__ __forceinline__ float bf2f(unsigned short h) {
    return __builtin_bit_cast(float, (unsigned int)h << 16);
}

// ---------------- K1: degree (atomic, rank captured) + W->bf16 conversion ------
// blocks [0, degB): deg+rank ; blocks [degB, degB+16): convert_w.
// rank[e] = this edge's arrival index within its row bucket (free from the
// atomicAdd return) -> scatter needs NO second atomic pass.
// wfrag[((kt*8+nt)*64 + lane)*8 + j] = W[kt*32 + (lane>>4)*8 + j][nt*16 + (lane&15)]

__global__ __launch_bounds__(256) void deg_convw_kernel(
    const int* __restrict__ row, int* __restrict__ deg, int* __restrict__ rank,
    int E, int degB,
    const float* __restrict__ W1, const float* __restrict__ W2,
    unsigned short* __restrict__ wfrag)
{
    if ((int)blockIdx.x < degB) {
        int e = blockIdx.x * 256 + threadIdx.x;
        if (e < E) rank[e] = atomicAdd(&deg[row[e]], 1);
    } else {
        int s = (blockIdx.x - degB) * 256 + threadIdx.x;   // 0..4095
        if (s >= 4096) return;
        int m  = s >> 11;
        int s2 = s & 2047;
        int kt = s2 >> 9;
        int nt = (s2 >> 6) & 7;
        int l  = s2 & 63;
        const float* W = m ? W2 : W1;
        unsigned short* o = wfrag + (size_t)m * 16384 + (size_t)s2 * 8;
        int k0 = kt * 32 + (l >> 4) * 8;
        int n0 = nt * 16 + (l & 15);
        #pragma unroll
        for (int j = 0; j < 8; ++j) o[j] = f2bf(W[(k0 + j) * DIM + n0]);
    }
}

// ---------------- K2: per-block exclusive scan over deg (+ fused dis) ----------

__global__ __launch_bounds__(256) void scan_block_kernel(const int* __restrict__ deg,
                                                         int* __restrict__ rowptr,
                                                         int* __restrict__ aux,
                                                         float* __restrict__ dis, int n) {
    __shared__ int ls[256];
    const int base = blockIdx.x * 1024;
    const int t = threadIdx.x;
    int v[4]; int s = 0;
    #pragma unroll
    for (int k = 0; k < 4; ++k) {
        int i = base + t * 4 + k;
        v[k] = (i < n) ? deg[i] : 0;
        s += v[k];
    }
    ls[t] = s;
    __syncthreads();
    for (int off = 1; off < 256; off <<= 1) {
        int x = (t >= off) ? ls[t - off] : 0;
        __syncthreads();
        ls[t] += x;
        __syncthreads();
    }
    int excl = ls[t] - s;
    if (t == 255) aux[blockIdx.x] = ls[255];
    #pragma unroll
    for (int k = 0; k < 4; ++k) {
        int i = base + t * 4 + k;
        if (i < n) {
            rowptr[i] = excl;
            dis[i] = rsqrtf((float)(v[k] + 1));   // +1 self-loop; always > 0
        }
        excl += v[k];
    }
}

// ---------------- K3: add aux prefix (computed per-block), build rp2 ----------
// Each block reduces aux[0..blockIdx-1] itself (<=255 entries, one LDS reduce).
// Writes rp2[i] = {start, end} packed (one 8B load downstream).

__global__ __launch_bounds__(256) void add_offsets_kernel(
    const int* __restrict__ rowptr, const int* __restrict__ deg,
    const int* __restrict__ aux, int2* __restrict__ rp2, int n)
{
    __shared__ int red[256];
    const int t = threadIdx.x;
    red[t] = (t < (int)blockIdx.x) ? aux[t] : 0;   // blockIdx <= 255 by construction
    __syncthreads();
    for (int off = 128; off > 0; off >>= 1) {
        if (t < off) red[t] += red[t + off];
        __syncthreads();
    }
    const int base = red[0];
    #pragma unroll
    for (int k = 0; k < 4; ++k) {
        int i = blockIdx.x * 1024 + t * 4 + k;
        if (i < n) {
            int st = rowptr[i] + base;
            rp2[i] = make_int2(st, st + deg[i]);
        }
    }
}

// ---------------- K4: scatter (atomic-free) INTERLEAVED with MFMA GEMM layer 1 --
// mod-5 block mapping: 3 scatter : 2 gemm (~2344:1563) so every CU holds a mix
// from t=0 (round-4 lesson: range partitioning = phase serialization, pipes idle).
// scatter: pos = rp2[r].x + rank[e]  (rank precomputed in K1 -> pure loads).

__global__ __launch_bounds__(256) void scatter_gemm1_kernel(
    // scatter args
    const int* __restrict__ row, const int* __restrict__ col,
    const int* __restrict__ rank, const float* __restrict__ dis,
    const int2* __restrict__ rp2, int2* __restrict__ epack, int E, int scatS,
    // gemm args
    const float* __restrict__ A, const unsigned short* __restrict__ wfrag,
    unsigned short* __restrict__ C, int n, int gemmG)
{
    const int grp = blockIdx.x / 5;
    const int off = blockIdx.x % 5;
    if (off < 3) {
        const int sId = grp * 3 + off;
        if (sId >= scatS) return;
        int e = sId * 256 + threadIdx.x;
        if (e >= E) return;
        int r = row[e], c = col[e];
        int pos = rp2[r].x + rank[e];
        float nrm = dis[r] * dis[c];
        epack[pos] = make_int2(c, __builtin_bit_cast(int, nrm));
    } else {
        const int gId = grp * 2 + (off - 3);
        if (gId >= gemmG) return;           // block-uniform, before any barrier
        __shared__ unsigned short sA[64][136];
        const int tid  = threadIdx.x;
        const int row0 = gId * 64;

        #pragma unroll
        for (int l = 0; l < 8; ++l) {
            int idx = tid + l * 256;
            int r   = idx >> 5;
            int c4  = (idx & 31) * 4;
            float4 v;
            if (row0 + r < n) v = *(const float4*)(A + (size_t)(row0 + r) * DIM + c4);
            else              v = make_float4(0.f, 0.f, 0.f, 0.f);
            unsigned int lo = (unsigned int)f2bf(v.x) | ((unsigned int)f2bf(v.y) << 16);
            unsigned int hi = (unsigned int)f2bf(v.z) | ((unsigned int)f2bf(v.w) << 16);
            *(uint2*)(&sA[r][c4]) = make_uint2(lo, hi);
        }
        __syncthreads();

        const int wave = tid >> 6;
        const int lane = tid & 63;
        const int m    = lane & 15;
        const int quad = lane >> 4;
        const int rowA = wave * 16 + m;

        short8 af[4];
        #pragma unroll
        for (int kt = 0; kt < 4; ++kt)
            af[kt] = *(const short8*)(&sA[rowA][kt * 32 + quad * 8]);

        floatx4 acc[8];
        #pragma unroll
        for (int nt = 0; nt < 8; ++nt) acc[nt] = (floatx4){0.f, 0.f, 0.f, 0.f};

        #pragma unroll
        for (int nt = 0; nt < 8; ++nt)
            #pragma unroll
            for (int kt = 0; kt < 4; ++kt) {
                short8 bfr = *(const short8*)(wfrag + ((size_t)(kt * 8 + nt) * 64 + lane) * 8);
                acc[nt] = __builtin_amdgcn_mfma_f32_16x16x32_bf16(af[kt], bfr, acc[nt], 0, 0, 0);
            }

        #pragma unroll
        for (int nt = 0; nt < 8; ++nt)
            #pragma unroll
            for (int r = 0; r < 4; ++r) {
                int rr = row0 + wave * 16 + quad * 4 + r;
                if (rr < n) C[(size_t)rr * DIM + nt * 16 + m] = f2bf(acc[nt][r]);
            }
    }
}

// ---------------- K6: MFMA GEMM, bf16 A input + fused BN/ReLU (layer 2) --------
// BN folded to scale/shift (precomputed in bn_finalize): relu(f*scale+shift)

__global__ __launch_bounds__(256) void gemm_mfma_bn_kernel(
    const unsigned short* __restrict__ A, const unsigned short* __restrict__ wfrag,
    unsigned short* __restrict__ C, int n,
    const float* __restrict__ mi)   // mi[0..127]=scale, mi[128..255]=shift
{
    __shared__ unsigned short sA[64][136];
    const int tid  = threadIdx.x;
    const int row0 = blockIdx.x * 64;

    #pragma unroll
    for (int l = 0; l < 4; ++l) {
        int idx = tid + l * 256;          // 0..1023, 16B chunks
        int r   = idx >> 4;
        int c8  = (idx & 15) * 8;
        uint4 u = make_uint4(0, 0, 0, 0);
        if (row0 + r < n) u = *(const uint4*)(A + (size_t)(row0 + r) * DIM + c8);
        float f[8] = { bf2f((unsigned short)(u.x & 0xffff)), bf2f((unsigned short)(u.x >> 16)),
                       bf2f((unsigned short)(u.y & 0xffff)), bf2f((unsigned short)(u.y >> 16)),
                       bf2f((unsigned short)(u.z & 0xffff)), bf2f((unsigned short)(u.z >> 16)),
                       bf2f((unsigned short)(u.w & 0xffff)), bf2f((unsigned short)(u.w >> 16)) };
        #pragma unroll
        for (int k = 0; k < 8; ++k) {
            int c = c8 + k;
            f[k] = fmaxf(fmaf(f[k], mi[c], mi[128 + c]), 0.f);
        }
        uint4 o;
        o.x = (unsigned int)f2bf(f[0]) | ((unsigned int)f2bf(f[1]) << 16);
        o.y = (unsigned int)f2bf(f[2]) | ((unsigned int)f2bf(f[3]) << 16);
        o.z = (unsigned int)f2bf(f[4]) | ((unsigned int)f2bf(f[5]) << 16);
        o.w = (unsigned int)f2bf(f[6]) | ((unsigned int)f2bf(f[7]) << 16);
        *(uint4*)(&sA[r][c8]) = o;
    }
    __syncthreads();

    const int wave = tid >> 6;
    const int lane = tid & 63;
    const int m    = lane & 15;
    const int quad = lane >> 4;
    const int rowA = wave * 16 + m;

    short8 af[4];
    #pragma unroll
    for (int kt = 0; kt < 4; ++kt)
        af[kt] = *(const short8*)(&sA[rowA][kt * 32 + quad * 8]);

    floatx4 acc[8];
    #pragma unroll
    for (int nt = 0; nt < 8; ++nt) acc[nt] = (floatx4){0.f, 0.f, 0.f, 0.f};

    #pragma unroll
    for (int nt = 0; nt < 8; ++nt)
        #pragma unroll
        for (int kt = 0; kt < 4; ++kt) {
            short8 bfr = *(const short8*)(wfrag + ((size_t)(kt * 8 + nt) * 64 + lane) * 8);
            acc[nt] = __builtin_amdgcn_mfma_f32_16x16x32_bf16(af[kt], bfr, acc[nt], 0, 0, 0);
        }

    #pragma unroll
    for (int nt = 0; nt < 8; ++nt)
        #pragma unroll
        for (int r = 0; r < 4; ++r) {
            int rr = row0 + wave * 16 + quad * 4 + r;
            if (rr < n) C[(size_t)rr * DIM + nt * 16 + m] = f2bf(acc[nt][r]);
        }
}

// ---------------- K5/K7: CSR aggregation ----------------
// 16 lanes/node, 8 ch/lane. out[i] = sum_e hw[col_e]*norm_e + hw[i]*dis_i^2 + bias.
// Uniform predicated unroll-8 loop: index clamped to pe-1, weight 0 for pad slots.
// STATS: LDS reduce + atomics over 64 spread copies. NO per-block threadfence
// (round-3 lesson: 6250x buffer_wbl2 serialized at the TCC = +620us).

__device__ __forceinline__ void acc8(float* acc, uint4 u, float w) {
    unsigned int a[4] = {u.x, u.y, u.z, u.w};
    #pragma unroll
    for (int k = 0; k < 4; ++k) {
        acc[2*k]   = fmaf(bf2f((unsigned short)(a[k] & 0xffff)), w, acc[2*k]);
        acc[2*k+1] = fmaf(bf2f((unsigned short)(a[k] >> 16)),    w, acc[2*k+1]);
    }
}

template <bool OUT_BF16, bool STATS>
__global__ __launch_bounds__(256) void agg_csr_kernel(
    const unsigned short* __restrict__ hw, const float* __restrict__ dis,
    const int2* __restrict__ rp2, const int2* __restrict__ epack,
    const float* __restrict__ bias, void* __restrict__ out_, int n,
    float* __restrict__ stat)
{
    const int sub  = threadIdx.x >> 4;        // 0..15 node slot in block
    const int l    = threadIdx.x & 15;
    const int node = blockIdx.x * 16 + sub;
    const bool valid = node < n;
    const int j = l * 8;

    float acc[8];
    #pragma unroll
    for (int k = 0; k < 8; ++k) acc[k] = 0.f;

    if (valid) {
        const int2 rp = rp2[node];            // one 8B load: {start, end}
        {   // self-loop term: hw[i] * dis_i^2
            const float d = dis[node];
            uint4 u = *(const uint4*)(hw + (size_t)node * DIM + j);
            acc8(acc, u, d * d);
        }

        const int pe = rp.y;
        for (int p = rp.x; p < pe; p += 8) {
            const int pm = pe - 1;
            int2 e[8];
            #pragma unroll
            for (int k = 0; k < 8; ++k) {
                int pk = p + k;
                e[k] = epack[pk < pm ? pk : pm];
            }
            uint4 u[8];
            #pragma unroll
            for (int k = 0; k < 8; ++k)
                u[k] = *(const uint4*)(hw + (size_t)e[k].x * DIM + j);
            #pragma unroll
            for (int k = 0; k < 8; ++k) {
                float w = (p + k < pe) ? __builtin_bit_cast(float, e[k].y) : 0.f;
                acc8(acc, u[k], w);
            }
        }

        float4 b0 = *(const float4*)(bias + j);
        float4 b1 = *(const float4*)(bias + j + 4);
        acc[0] += b0.x; acc[1] += b0.y; acc[2] += b0.z; acc[3] += b0.w;
        acc[4] += b1.x; acc[5] += b1.y; acc[6] += b1.z; acc[7] += b1.w;

        if (OUT_BF16) {
            unsigned short* out = (unsigned short*)out_;
            uint4 o;
            o.x = (unsigned int)f2bf(acc[0]) | ((unsigned int)f2bf(acc[1]) << 16);
            o.y = (unsigned int)f2bf(acc[2]) | ((unsigned int)f2bf(acc[3]) << 16);
            o.z = (unsigned int)f2bf(acc[4]) | ((unsigned int)f2bf(acc[5]) << 16);
            o.w = (unsigned int)f2bf(acc[6]) | ((unsigned int)f2bf(acc[7]) << 16);
            *(uint4*)(out + (size_t)node * DIM + j) = o;
        } else {
            float* out = (float*)out_;
            *(float4*)(out + (size_t)node * DIM + j)     = make_float4(acc[0], acc[1], acc[2], acc[3]);
            *(float4*)(out + (size_t)node * DIM + j + 4) = make_float4(acc[4], acc[5], acc[6], acc[7]);
        }
    }

    if constexpr (STATS) {
        // row padded to 257 floats: 4-way write conflicts max, reads ~free.
        __shared__ float red[16][257];
        #pragma unroll
        for (int k = 0; k < 8; ++k) {
            float a = valid ? acc[k] : 0.f;
            red[sub][j + k]       = a;
            red[sub][128 + j + k] = a * a;
        }
        __syncthreads();
        float t = 0.f;
        #pragma unroll
        for (int r = 0; r < 16; ++r) t += red[r][threadIdx.x];
        atomicAdd(&stat[(blockIdx.x & (STAT_COPIES - 1)) * 256 + threadIdx.x], t);
    }
}

// ---------------- BN finalize: fold stats into scale/shift ----------------

__global__ void bn_finalize_kernel(const float* __restrict__ stat,
                                   const float* __restrict__ gamma,
                                   const float* __restrict__ beta,
                                   float* __restrict__ mi, int n) {
    int c = threadIdx.x;
    if (c < DIM) {
        float s = 0.f, q = 0.f;
        #pragma unroll 4
        for (int cp = 0; cp < STAT_COPIES; ++cp) {
            s += stat[cp * 256 + c];
            q += stat[cp * 256 + 128 + c];
        }
        float mean  = s / (float)n;
        float var   = q / (float)n - mean * mean;
        float istd  = rsqrtf(var + BN_EPS);
        float scale = gamma[c] * istd;
        mi[c]       = scale;
        mi[DIM + c] = fmaf(-mean, scale, beta[c]);   // shift
    }
}

// ---------------- launch ----------------

extern "C" void kernel_launch(void* const* d_in, const int* in_sizes, int n_in,
                              void* d_out, int out_size, void* d_ws, size_t ws_size,
                              hipStream_t stream)
{
    const float* x      = (const float*)d_in[0];
    const int*   ei     = (const int*)  d_in[1];
    const float* W1     = (const float*)d_in[2];
    const float* b1     = (const float*)d_in[3];
    const float* gamma1 = (const float*)d_in[4];
    const float* beta1  = (const float*)d_in[5];
    const float* W2     = (const float*)d_in[6];
    const float* b2     = (const float*)d_in[7];
    float* out = (float*)d_out;

    const int N = in_sizes[0] / DIM;   // 100000
    const int E = in_sizes[1] / 2;     // 600000
    const int* row = ei;
    const int* col = ei + E;

    const int NB    = (N + 1023) / 1024;   // <= 256 (N <= 262144)
    const int degB  = (E + 255) / 256;
    const int gemmB = (N + 63) / 64;
    const int aggB  = (N + 15) / 16;
    // interleaved K4 grid: groups of 5 = 3 scatter + 2 gemm
    const int k4B   = 5 * max((degB + 2) / 3, (gemmB + 1) / 2);

    // Workspace layout (8B-alignment-safe ordering). Zeroed region is contiguous:
    unsigned short* hw    = (unsigned short*)d_ws;         // N*128 bf16
    unsigned short* h1    = hw + (size_t)N * DIM;          // N*128 bf16
    int2*  epack  = (int2*)(h1 + (size_t)N * DIM);         // E (8B each)
    int2*  rp2    = epack + E;                             // N {start,end}
    unsigned short* wfrag = (unsigned short*)(rp2 + N);    // 2*16384 bf16
    float* dis    = (float*)(wfrag + 2 * 16384);           // N
    int*   rank   = (int*)(dis + N);                       // E (edge rank in bucket)
    int*   rowptr = rank + E;                              // N (scratch, per-block scan)
    int*   aux    = rowptr + N;                            // 256
    float* mi     = (float*)(aux + 256);                   // 256
    // ---- zeroed region start ----
    int*   deg    = (int*)(mi + 256);                      // N
    float* stat   = (float*)(deg + N);                     // 64*256
    const size_t zero_bytes = (size_t)N * 4 + (size_t)STAT_COPIES * 256 * 4;

    hipMemsetAsync(deg, 0, zero_bytes, stream);

    // K1: degree atomics (rank captured) + W conversion
    deg_convw_kernel<<<degB + 16, 256, 0, stream>>>(row, deg, rank, E, degB, W1, W2, wfrag);
    // K2: per-block exclusive scan (+ dis)
    scan_block_kernel<<<NB, 256, 0, stream>>>(deg, rowptr, aux, dis, N);
    // K3: cross-block offsets (self-computed aux prefix) -> rp2
    add_offsets_kernel<<<NB, 256, 0, stream>>>(rowptr, deg, aux, rp2, N);
    // K4: atomic-free scatter interleaved (mod-5) with gemm1
    scatter_gemm1_kernel<<<k4B, 256, 0, stream>>>(row, col, rank, dis, rp2, epack, E, degB,
                                                  x, wfrag, hw, N, gemmB);
    // K5: agg layer 1 + fused BN stats (spread atomics, no fence)
    agg_csr_kernel<true, true><<<aggB, 256, 0, stream>>>(hw, dis, rp2, epack, b1, h1, N,
                                                         stat);
    // K5b: fold stats -> BN scale/shift (1 tiny block; kernel boundary = coherence)
    bn_finalize_kernel<<<1, DIM, 0, stream>>>(stat, gamma1, beta1, mi, N);
    // K6: gemm2 with fused BN(scale,shift)+ReLU on input
    gemm_mfma_bn_kernel<<<gemmB, 256, 0, stream>>>(h1, wfrag + 16384, hw, N, mi);
    // K7: agg layer 2 -> fp32 output
    agg_csr_kernel<false, false><<<aggB, 256, 0, stream>>>(hw, dis, rp2, epack, b2, out, N,
                                                           nullptr);
}

// Round 6
// 261.942 us; speedup vs baseline: 3.3702x; 1.0028x over previous
//
#include <hip/hip_runtime.h>

#define DIM 128
#define BN_EPS 1e-5f
#define STAT_COPIES 64

typedef short short8 __attribute__((ext_vector_type(8)));   // 8 bf16 bit patterns
typedef float floatx4 __attribute__((ext_vector_type(4)));

__device__ __forceinline__ unsigned short f2bf(float f) {
    unsigned int u = __builtin_bit_cast(unsigned int, f);
    u += 0x7FFFu + ((u >> 16) & 1u);          // RNE (inputs are finite)
    return (unsigned short)(u >> 16);
}
__device__ __forceinline__ float bf2f(unsigned short h) {
    return __builtin_bit_cast(float, (unsigned int)h << 16);
}

// ---------------- K1: degree (atomic, rank captured) + W->bf16 conversion ------
// rank[e] = edge's arrival index within its row bucket (free from atomicAdd
// return) -> scatter needs no second atomic pass.
// wfrag[((kt*8+nt)*64 + lane)*8 + j] = W[kt*32 + (lane>>4)*8 + j][nt*16 + (lane&15)]

__global__ __launch_bounds__(256) void deg_convw_kernel(
    const int* __restrict__ row, int* __restrict__ deg, int* __restrict__ rank,
    int E, int degB,
    const float* __restrict__ W1, const float* __restrict__ W2,
    unsigned short* __restrict__ wfrag)
{
    if ((int)blockIdx.x < degB) {
        int e = blockIdx.x * 256 + threadIdx.x;
        if (e < E) rank[e] = atomicAdd(&deg[row[e]], 1);
    } else {
        int s = (blockIdx.x - degB) * 256 + threadIdx.x;   // 0..4095
        if (s >= 4096) return;
        int m  = s >> 11;
        int s2 = s & 2047;
        int kt = s2 >> 9;
        int nt = (s2 >> 6) & 7;
        int l  = s2 & 63;
        const float* W = m ? W2 : W1;
        unsigned short* o = wfrag + (size_t)m * 16384 + (size_t)s2 * 8;
        int k0 = kt * 32 + (l >> 4) * 8;
        int n0 = nt * 16 + (l & 15);
        #pragma unroll
        for (int j = 0; j < 8; ++j) o[j] = f2bf(W[(k0 + j) * DIM + n0]);
    }
}

// ---------------- K2: per-block exclusive scan over deg (+ fused dis) ----------

__global__ __launch_bounds__(256) void scan_block_kernel(const int* __restrict__ deg,
                                                         int* __restrict__ rowptr,
                                                         int* __restrict__ aux,
                                                         float* __restrict__ dis, int n) {
    __shared__ int ls[256];
    const int base = blockIdx.x * 1024;
    const int t = threadIdx.x;
    int v[4]; int s = 0;
    #pragma unroll
    for (int k = 0; k < 4; ++k) {
        int i = base + t * 4 + k;
        v[k] = (i < n) ? deg[i] : 0;
        s += v[k];
    }
    ls[t] = s;
    __syncthreads();
    for (int off = 1; off < 256; off <<= 1) {
        int x = (t >= off) ? ls[t - off] : 0;
        __syncthreads();
        ls[t] += x;
        __syncthreads();
    }
    int excl = ls[t] - s;
    if (t == 255) aux[blockIdx.x] = ls[255];
    #pragma unroll
    for (int k = 0; k < 4; ++k) {
        int i = base + t * 4 + k;
        if (i < n) {
            rowptr[i] = excl;
            dis[i] = rsqrtf((float)(v[k] + 1));   // +1 self-loop; always > 0
        }
        excl += v[k];
    }
}

// ---------------- K3: add aux prefix (computed per-block), build rp2 ----------

__global__ __launch_bounds__(256) void add_offsets_kernel(
    const int* __restrict__ rowptr, const int* __restrict__ deg,
    const int* __restrict__ aux, int2* __restrict__ rp2, int n)
{
    __shared__ int red[256];
    const int t = threadIdx.x;
    red[t] = (t < (int)blockIdx.x) ? aux[t] : 0;   // blockIdx <= 255 by construction
    __syncthreads();
    for (int off = 128; off > 0; off >>= 1) {
        if (t < off) red[t] += red[t + off];
        __syncthreads();
    }
    const int base = red[0];
    #pragma unroll
    for (int k = 0; k < 4; ++k) {
        int i = blockIdx.x * 1024 + t * 4 + k;
        if (i < n) {
            int st = rowptr[i] + base;
            rp2[i] = make_int2(st, st + deg[i]);
        }
    }
}

// ---------------- K4: scatter (atomic-free) INTERLEAVED with MFMA GEMM layer 1 --
// mod-5 block mapping: 3 scatter : 2 gemm so every CU holds a mix from t=0.
// GEMM: NO LDS staging (round-5 lesson: A is used exactly once, fragment slices
// are contiguous in global) -> direct fragment loads, no barrier, LDS=0.

__global__ __launch_bounds__(256) void scatter_gemm1_kernel(
    const int* __restrict__ row, const int* __restrict__ col,
    const int* __restrict__ rank, const float* __restrict__ dis,
    const int2* __restrict__ rp2, int2* __restrict__ epack, int E, int scatS,
    const float* __restrict__ A, const unsigned short* __restrict__ wfrag,
    unsigned short* __restrict__ C, int n, int gemmG)
{
    const int grp = blockIdx.x / 5;
    const int off = blockIdx.x % 5;
    if (off < 3) {
        const int sId = grp * 3 + off;
        if (sId >= scatS) return;
        int e = sId * 256 + threadIdx.x;
        if (e >= E) return;
        int r = row[e], c = col[e];
        int pos = rp2[r].x + rank[e];
        float nrm = dis[r] * dis[c];
        epack[pos] = make_int2(c, __builtin_bit_cast(int, nrm));
    } else {
        const int gId = grp * 2 + (off - 3);
        if (gId >= gemmG) return;
        const int tid  = threadIdx.x;
        const int row0 = gId * 64;
        const int wave = tid >> 6;
        const int lane = tid & 63;
        const int m    = lane & 15;
        const int quad = lane >> 4;
        const int rowA = row0 + wave * 16 + m;

        short8 af[4];
        if (rowA < n) {
            #pragma unroll
            for (int kt = 0; kt < 4; ++kt) {
                const float* src = A + (size_t)rowA * DIM + kt * 32 + quad * 8;
                float4 v0 = *(const float4*)(src);
                float4 v1 = *(const float4*)(src + 4);
                af[kt] = (short8){ (short)f2bf(v0.x), (short)f2bf(v0.y),
                                   (short)f2bf(v0.z), (short)f2bf(v0.w),
                                   (short)f2bf(v1.x), (short)f2bf(v1.y),
                                   (short)f2bf(v1.z), (short)f2bf(v1.w) };
            }
        } else {
            #pragma unroll
            for (int kt = 0; kt < 4; ++kt) af[kt] = (short8){0,0,0,0,0,0,0,0};
        }

        floatx4 acc[8];
        #pragma unroll
        for (int nt = 0; nt < 8; ++nt) acc[nt] = (floatx4){0.f, 0.f, 0.f, 0.f};

        #pragma unroll
        for (int nt = 0; nt < 8; ++nt)
            #pragma unroll
            for (int kt = 0; kt < 4; ++kt) {
                short8 bfr = *(const short8*)(wfrag + ((size_t)(kt * 8 + nt) * 64 + lane) * 8);
                acc[nt] = __builtin_amdgcn_mfma_f32_16x16x32_bf16(af[kt], bfr, acc[nt], 0, 0, 0);
            }

        #pragma unroll
        for (int nt = 0; nt < 8; ++nt)
            #pragma unroll
            for (int r = 0; r < 4; ++r) {
                int rr = row0 + wave * 16 + quad * 4 + r;
                if (rr < n) C[(size_t)rr * DIM + nt * 16 + m] = f2bf(acc[nt][r]);
            }
    }
}

// ---------------- K6: MFMA GEMM layer 2, direct bf16 fragment loads ------------
// BN scale/shift + ReLU applied in-register on the A fragment (identical math to
// the old LDS-staging path; no LDS, no barrier).

__global__ __launch_bounds__(256) void gemm_mfma_bn_kernel(
    const unsigned short* __restrict__ Abf, const unsigned short* __restrict__ wfrag,
    unsigned short* __restrict__ C, int n,
    const float* __restrict__ mi)   // mi[0..127]=scale, mi[128..255]=shift
{
    const int tid  = threadIdx.x;
    const int row0 = blockIdx.x * 64;
    const int wave = tid >> 6;
    const int lane = tid & 63;
    const int m    = lane & 15;
    const int quad = lane >> 4;
    const int rowA = row0 + wave * 16 + m;

    short8 af[4];
    if (rowA < n) {
        #pragma unroll
        for (int kt = 0; kt < 4; ++kt) {
            const int c0 = kt * 32 + quad * 8;
            short8 v = *(const short8*)(Abf + (size_t)rowA * DIM + c0);
            float4 s0 = *(const float4*)(mi + c0);
            float4 s1 = *(const float4*)(mi + c0 + 4);
            float4 h0 = *(const float4*)(mi + 128 + c0);
            float4 h1 = *(const float4*)(mi + 128 + c0 + 4);
            float f[8];
            #pragma unroll
            for (int j = 0; j < 8; ++j) f[j] = bf2f((unsigned short)v[j]);
            f[0] = fmaxf(fmaf(f[0], s0.x, h0.x), 0.f);
            f[1] = fmaxf(fmaf(f[1], s0.y, h0.y), 0.f);
            f[2] = fmaxf(fmaf(f[2], s0.z, h0.z), 0.f);
            f[3] = fmaxf(fmaf(f[3], s0.w, h0.w), 0.f);
            f[4] = fmaxf(fmaf(f[4], s1.x, h1.x), 0.f);
            f[5] = fmaxf(fmaf(f[5], s1.y, h1.y), 0.f);
            f[6] = fmaxf(fmaf(f[6], s1.z, h1.z), 0.f);
            f[7] = fmaxf(fmaf(f[7], s1.w, h1.w), 0.f);
            af[kt] = (short8){ (short)f2bf(f[0]), (short)f2bf(f[1]),
                               (short)f2bf(f[2]), (short)f2bf(f[3]),
                               (short)f2bf(f[4]), (short)f2bf(f[5]),
                               (short)f2bf(f[6]), (short)f2bf(f[7]) };
        }
    } else {
        #pragma unroll
        for (int kt = 0; kt < 4; ++kt) af[kt] = (short8){0,0,0,0,0,0,0,0};
    }

    floatx4 acc[8];
    #pragma unroll
    for (int nt = 0; nt < 8; ++nt) acc[nt] = (floatx4){0.f, 0.f, 0.f, 0.f};

    #pragma unroll
    for (int nt = 0; nt < 8; ++nt)
        #pragma unroll
        for (int kt = 0; kt < 4; ++kt) {
            short8 bfr = *(const short8*)(wfrag + ((size_t)(kt * 8 + nt) * 64 + lane) * 8);
            acc[nt] = __builtin_amdgcn_mfma_f32_16x16x32_bf16(af[kt], bfr, acc[nt], 0, 0, 0);
        }

    #pragma unroll
    for (int nt = 0; nt < 8; ++nt)
        #pragma unroll
        for (int r = 0; r < 4; ++r) {
            int rr = row0 + wave * 16 + quad * 4 + r;
            if (rr < n) C[(size_t)rr * DIM + nt * 16 + m] = f2bf(acc[nt][r]);
        }
}

// ---------------- K5/K7: CSR aggregation ----------------
// 16 lanes/node, 8 ch/lane. out[i] = sum_e hw[col_e]*norm_e + hw[i]*dis_i^2 + bias.
// Uniform predicated unroll-8 loop: index clamped to pe-1, weight 0 for pad slots.
// STATS: LDS reduce + atomics over 64 spread copies. NO per-block threadfence
// (round-3 lesson: 6250x buffer_wbl2 serialized at the TCC = +620us).

__device__ __forceinline__ void acc8(float* acc, uint4 u, float w) {
    unsigned int a[4] = {u.x, u.y, u.z, u.w};
    #pragma unroll
    for (int k = 0; k < 4; ++k) {
        acc[2*k]   = fmaf(bf2f((unsigned short)(a[k] & 0xffff)), w, acc[2*k]);
        acc[2*k+1] = fmaf(bf2f((unsigned short)(a[k] >> 16)),    w, acc[2*k+1]);
    }
}

template <bool OUT_BF16, bool STATS>
__global__ __launch_bounds__(256) void agg_csr_kernel(
    const unsigned short* __restrict__ hw, const float* __restrict__ dis,
    const int2* __restrict__ rp2, const int2* __restrict__ epack,
    const float* __restrict__ bias, void* __restrict__ out_, int n,
    float* __restrict__ stat)
{
    const int sub  = threadIdx.x >> 4;        // 0..15 node slot in block
    const int l    = threadIdx.x & 15;
    const int node = blockIdx.x * 16 + sub;
    const bool valid = node < n;
    const int j = l * 8;

    float acc[8];
    #pragma unroll
    for (int k = 0; k < 8; ++k) acc[k] = 0.f;

    if (valid) {
        const int2 rp = rp2[node];            // one 8B load: {start, end}
        {   // self-loop term: hw[i] * dis_i^2
            const float d = dis[node];
            uint4 u = *(const uint4*)(hw + (size_t)node * DIM + j);
            acc8(acc, u, d * d);
        }

        const int pe = rp.y;
        for (int p = rp.x; p < pe; p += 8) {
            const int pm = pe - 1;
            int2 e[8];
            #pragma unroll
            for (int k = 0; k < 8; ++k) {
                int pk = p + k;
                e[k] = epack[pk < pm ? pk : pm];
            }
            uint4 u[8];
            #pragma unroll
            for (int k = 0; k < 8; ++k)
                u[k] = *(const uint4*)(hw + (size_t)e[k].x * DIM + j);
            #pragma unroll
            for (int k = 0; k < 8; ++k) {
                float w = (p + k < pe) ? __builtin_bit_cast(float, e[k].y) : 0.f;
                acc8(acc, u[k], w);
            }
        }

        float4 b0 = *(const float4*)(bias + j);
        float4 b1 = *(const float4*)(bias + j + 4);
        acc[0] += b0.x; acc[1] += b0.y; acc[2] += b0.z; acc[3] += b0.w;
        acc[4] += b1.x; acc[5] += b1.y; acc[6] += b1.z; acc[7] += b1.w;

        if (OUT_BF16) {
            unsigned short* out = (unsigned short*)out_;
            uint4 o;
            o.x = (unsigned int)f2bf(acc[0]) | ((unsigned int)f2bf(acc[1]) << 16);
            o.y = (unsigned int)f2bf(acc[2]) | ((unsigned int)f2bf(acc[3]) << 16);
            o.z = (unsigned int)f2bf(acc[4]) | ((unsigned int)f2bf(acc[5]) << 16);
            o.w = (unsigned int)f2bf(acc[6]) | ((unsigned int)f2bf(acc[7]) << 16);
            *(uint4*)(out + (size_t)node * DIM + j) = o;
        } else {
            float* out = (float*)out_;
            *(float4*)(out + (size_t)node * DIM + j)     = make_float4(acc[0], acc[1], acc[2], acc[3]);
            *(float4*)(out + (size_t)node * DIM + j + 4) = make_float4(acc[4], acc[5], acc[6], acc[7]);
        }
    }

    if constexpr (STATS) {
        // row padded to 257 floats: 4-way write conflicts max, reads ~free.
        __shared__ float red[16][257];
        #pragma unroll
        for (int k = 0; k < 8; ++k) {
            float a = valid ? acc[k] : 0.f;
            red[sub][j + k]       = a;
            red[sub][128 + j + k] = a * a;
        }
        __syncthreads();
        float t = 0.f;
        #pragma unroll
        for (int r = 0; r < 16; ++r) t += red[r][threadIdx.x];
        atomicAdd(&stat[(blockIdx.x & (STAT_COPIES - 1)) * 256 + threadIdx.x], t);
    }
}

// ---------------- BN finalize: fold stats into scale/shift ----------------

__global__ void bn_finalize_kernel(const float* __restrict__ stat,
                                   const float* __restrict__ gamma,
                                   const float* __restrict__ beta,
                                   float* __restrict__ mi, int n) {
    int c = threadIdx.x;
    if (c < DIM) {
        float s = 0.f, q = 0.f;
        #pragma unroll 4
        for (int cp = 0; cp < STAT_COPIES; ++cp) {
            s += stat[cp * 256 + c];
            q += stat[cp * 256 + 128 + c];
        }
        float mean  = s / (float)n;
        float var   = q / (float)n - mean * mean;
        float istd  = rsqrtf(var + BN_EPS);
        float scale = gamma[c] * istd;
        mi[c]       = scale;
        mi[DIM + c] = fmaf(-mean, scale, beta[c]);   // shift
    }
}

// ---------------- launch ----------------

extern "C" void kernel_launch(void* const* d_in, const int* in_sizes, int n_in,
                              void* d_out, int out_size, void* d_ws, size_t ws_size,
                              hipStream_t stream)
{
    const float* x      = (const float*)d_in[0];
    const int*   ei     = (const int*)  d_in[1];
    const float* W1     = (const float*)d_in[2];
    const float* b1     = (const float*)d_in[3];
    const float* gamma1 = (const float*)d_in[4];
    const float* beta1  = (const float*)d_in[5];
    const float* W2     = (const float*)d_in[6];
    const float* b2     = (const float*)d_in[7];
    float* out = (float*)d_out;

    const int N = in_sizes[0] / DIM;   // 100000
    const int E = in_sizes[1] / 2;     // 600000
    const int* row = ei;
    const int* col = ei + E;

    const int NB    = (N + 1023) / 1024;   // <= 256 (N <= 262144)
    const int degB  = (E + 255) / 256;
    const int gemmB = (N + 63) / 64;
    const int aggB  = (N + 15) / 16;
    // interleaved K4 grid: groups of 5 = 3 scatter + 2 gemm
    const int k4B   = 5 * max((degB + 2) / 3, (gemmB + 1) / 2);

    // Workspace layout (8B-alignment-safe ordering). Zeroed region is contiguous:
    unsigned short* hw    = (unsigned short*)d_ws;         // N*128 bf16
    unsigned short* h1    = hw + (size_t)N * DIM;          // N*128 bf16
    int2*  epack  = (int2*)(h1 + (size_t)N * DIM);         // E (8B each)
    int2*  rp2    = epack + E;                             // N {start,end}
    unsigned short* wfrag = (unsigned short*)(rp2 + N);    // 2*16384 bf16
    float* dis    = (float*)(wfrag + 2 * 16384);           // N
    int*   rank   = (int*)(dis + N);                       // E (edge rank in bucket)
    int*   rowptr = rank + E;                              // N (scratch, per-block scan)
    int*   aux    = rowptr + N;                            // 256
    float* mi     = (float*)(aux + 256);                   // 256
    // ---- zeroed region start ----
    int*   deg    = (int*)(mi + 256);                      // N
    float* stat   = (float*)(deg + N);                     // 64*256
    const size_t zero_bytes = (size_t)N * 4 + (size_t)STAT_COPIES * 256 * 4;

    hipMemsetAsync(deg, 0, zero_bytes, stream);

    // K1: degree atomics (rank captured) + W conversion
    deg_convw_kernel<<<degB + 16, 256, 0, stream>>>(row, deg, rank, E, degB, W1, W2, wfrag);
    // K2: per-block exclusive scan (+ dis)
    scan_block_kernel<<<NB, 256, 0, stream>>>(deg, rowptr, aux, dis, N);
    // K3: cross-block offsets (self-computed aux prefix) -> rp2
    add_offsets_kernel<<<NB, 256, 0, stream>>>(rowptr, deg, aux, rp2, N);
    // K4: atomic-free scatter interleaved (mod-5) with LDS-free gemm1
    scatter_gemm1_kernel<<<k4B, 256, 0, stream>>>(row, col, rank, dis, rp2, epack, E, degB,
                                                  x, wfrag, hw, N, gemmB);
    // K5: agg layer 1 + fused BN stats (spread atomics, no fence)
    agg_csr_kernel<true, true><<<aggB, 256, 0, stream>>>(hw, dis, rp2, epack, b1, h1, N,
                                                         stat);
    // K5b: fold stats -> BN scale/shift (1 tiny block; kernel boundary = coherence)
    bn_finalize_kernel<<<1, DIM, 0, stream>>>(stat, gamma1, beta1, mi, N);
    // K6: gemm2 with in-register BN(scale,shift)+ReLU, LDS-free
    gemm_mfma_bn_kernel<<<gemmB, 256, 0, stream>>>(h1, wfrag + 16384, hw, N, mi);
    // K7: agg layer 2 -> fp32 output
    agg_csr_kernel<false, false><<<aggB, 256, 0, stream>>>(hw, dis, rp2, epack, b2, out, N,
                                                           nullptr);
}